// Round 1
// baseline (353.047 us; speedup 1.0000x reference)
//
#include <hip/hip_runtime.h>
#include <hip/hip_bf16.h>
#include <cstdint>

// ---------------------------------------------------------------------------
// GNN encoder: 3 x { agg = segment_sum(z[src], dst); h = z + agg;
//                    t = relu(h@w1+b1); z = relu(t@w2+b2) }
// Strategy: build CSR (dst -> list of src) on device each call, then
// aggregation is a per-node gather (no float atomics). fp32 everywhere.
// ---------------------------------------------------------------------------

#define NNODES 10000
#define NEDGES 320000
#define DIN 128
#define DH 256

// --- edge_index storage detection: int64 stored little-endian has zero high
// words (values < 10000). If any odd 32-bit word among the first samples is
// nonzero, storage is int32. Deterministic, runs every call.
__global__ void detect_i32_kernel(const int* __restrict__ eb, int nsample, int* __restrict__ flag) {
    __shared__ int any;
    if (threadIdx.x == 0) any = 0;
    __syncthreads();
    for (int i = threadIdx.x; i < nsample; i += blockDim.x)
        if (eb[2 * i + 1] != 0) any = 1;
    __syncthreads();
    if (threadIdx.x == 0) flag[0] = any;   // 1 => int32 storage, 0 => int64
}

__device__ __forceinline__ int eload(const int* __restrict__ eb, int is32, long logical_idx) {
    return is32 ? eb[logical_idx] : eb[2 * logical_idx]; // little-endian low word
}

__global__ void zero_i_kernel(int* __restrict__ p, int n) {
    int i = blockIdx.x * blockDim.x + threadIdx.x;
    if (i < n) p[i] = 0;
}

__global__ void hist_kernel(const int* __restrict__ eb, const int* __restrict__ flag,
                            int* __restrict__ cnt, int E) {
    int i = blockIdx.x * blockDim.x + threadIdx.x;
    if (i >= E) return;
    int is32 = flag[0];
    int d = eload(eb, is32, (long)E + i);
    atomicAdd(&cnt[d], 1);
}

// single-block exclusive scan over N counts -> offs[N+1], cursor copy
__global__ __launch_bounds__(1024) void scan_kernel(const int* __restrict__ cnt,
                                                    int* __restrict__ offs,
                                                    int* __restrict__ cursor, int n) {
    __shared__ int sums[1024];
    int tid = threadIdx.x;
    int per = (n + 1023) / 1024;          // 10 for n=10000
    int beg = tid * per;
    int local[16];
    int s = 0;
    for (int i = 0; i < per; ++i) {
        int idx = beg + i;
        int v = (idx < n) ? cnt[idx] : 0;
        local[i] = s;
        s += v;
    }
    sums[tid] = s;
    __syncthreads();
    for (int d = 1; d < 1024; d <<= 1) {
        int y = (tid >= d) ? sums[tid - d] : 0;
        __syncthreads();
        sums[tid] += y;
        __syncthreads();
    }
    int base = sums[tid] - s;             // exclusive prefix of this thread's chunk
    for (int i = 0; i < per; ++i) {
        int idx = beg + i;
        if (idx < n) {
            int v = base + local[i];
            offs[idx] = v;
            cursor[idx] = v;
        }
    }
    if (tid == 1023) offs[n] = sums[1023];
}

__global__ void scatter_kernel(const int* __restrict__ eb, const int* __restrict__ flag,
                               int* __restrict__ cursor, int* __restrict__ srcs, int E) {
    int i = blockIdx.x * blockDim.x + threadIdx.x;
    if (i >= E) return;
    int is32 = flag[0];
    int s = eload(eb, is32, (long)i);
    int d = eload(eb, is32, (long)E + i);
    int pos = atomicAdd(&cursor[d], 1);
    srcs[pos] = s;
}

// --- aggregation: h[i] = z[i] + sum_{e in CSR[i]} z[src_e].  One wave/node,
// 4 nodes per 256-thread block. float4 (D=256) / float2 (D=128) lane loads.
template <int D>
__global__ __launch_bounds__(256) void agg_add_kernel(const float* __restrict__ z,
                                                      const int* __restrict__ srcs,
                                                      const int* __restrict__ offs,
                                                      float* __restrict__ h, int n) {
    int node = blockIdx.x * 4 + (threadIdx.x >> 6);
    if (node >= n) return;
    int lane = threadIdx.x & 63;
    int beg = offs[node], end = offs[node + 1];
    if constexpr (D == 256) {
        float4 acc = make_float4(0.f, 0.f, 0.f, 0.f);
        for (int e = beg; e < end; ++e) {
            int s = srcs[e];
            float4 v = reinterpret_cast<const float4*>(z + (size_t)s * D)[lane];
            acc.x += v.x; acc.y += v.y; acc.z += v.z; acc.w += v.w;
        }
        float4 zr = reinterpret_cast<const float4*>(z + (size_t)node * D)[lane];
        float4 o = make_float4(zr.x + acc.x, zr.y + acc.y, zr.z + acc.z, zr.w + acc.w);
        reinterpret_cast<float4*>(h + (size_t)node * D)[lane] = o;
    } else {
        float2 acc = make_float2(0.f, 0.f);
        for (int e = beg; e < end; ++e) {
            int s = srcs[e];
            float2 v = reinterpret_cast<const float2*>(z + (size_t)s * D)[lane];
            acc.x += v.x; acc.y += v.y;
        }
        float2 zr = reinterpret_cast<const float2*>(z + (size_t)node * D)[lane];
        float2 o = make_float2(zr.x + acc.x, zr.y + acc.y);
        reinterpret_cast<float2*>(h + (size_t)node * D)[lane] = o;
    }
}

// --- fp32 GEMM C = relu(A @ W + bias); A: MxK, W: KxNc (row-major), C: MxNc.
// 64x64 tile, BK=16, 256 threads, 4x4 microtile.
__global__ __launch_bounds__(256) void gemm_bias_relu_kernel(const float* __restrict__ A,
                                                             const float* __restrict__ W,
                                                             const float* __restrict__ bias,
                                                             float* __restrict__ C,
                                                             int M, int Nc, int K) {
    __shared__ float As[64][16];
    __shared__ float Ws[16][64];
    int tid = threadIdx.x;
    int tx = tid & 15, ty = tid >> 4;
    int m0 = blockIdx.x * 64;
    int n0 = blockIdx.y * 64;
    float acc[4][4] = {};
    for (int k0 = 0; k0 < K; k0 += 16) {
        { // stage A tile (64x16) : one float4 per thread
            int r = tid >> 2;
            int c4 = (tid & 3) * 4;
            int gr = m0 + r;
            float4 v = make_float4(0.f, 0.f, 0.f, 0.f);
            if (gr < M) v = *reinterpret_cast<const float4*>(&A[(size_t)gr * K + k0 + c4]);
            As[r][c4 + 0] = v.x; As[r][c4 + 1] = v.y; As[r][c4 + 2] = v.z; As[r][c4 + 3] = v.w;
        }
        { // stage W tile (16x64) : one float4 per thread
            int rw = tid >> 4;
            int cw = (tid & 15) * 4;
            float4 wv = *reinterpret_cast<const float4*>(&W[(size_t)(k0 + rw) * Nc + n0 + cw]);
            Ws[rw][cw + 0] = wv.x; Ws[rw][cw + 1] = wv.y; Ws[rw][cw + 2] = wv.z; Ws[rw][cw + 3] = wv.w;
        }
        __syncthreads();
#pragma unroll
        for (int kk = 0; kk < 16; ++kk) {
            float a[4], b[4];
#pragma unroll
            for (int i = 0; i < 4; ++i) a[i] = As[ty * 4 + i][kk];
#pragma unroll
            for (int j = 0; j < 4; ++j) b[j] = Ws[kk][tx * 4 + j];
#pragma unroll
            for (int i = 0; i < 4; ++i)
#pragma unroll
                for (int j = 0; j < 4; ++j) acc[i][j] += a[i] * b[j];
        }
        __syncthreads();
    }
    int gc = n0 + tx * 4;
    float4 bv = *reinterpret_cast<const float4*>(&bias[gc]);
#pragma unroll
    for (int i = 0; i < 4; ++i) {
        int gr = m0 + ty * 4 + i;
        if (gr >= M) break;
        float4 o;
        o.x = fmaxf(acc[i][0] + bv.x, 0.f);
        o.y = fmaxf(acc[i][1] + bv.y, 0.f);
        o.z = fmaxf(acc[i][2] + bv.z, 0.f);
        o.w = fmaxf(acc[i][3] + bv.w, 0.f);
        *reinterpret_cast<float4*>(&C[(size_t)gr * Nc + gc]) = o;
    }
}

extern "C" void kernel_launch(void* const* d_in, const int* in_sizes, int n_in,
                              void* d_out, int out_size, void* d_ws, size_t ws_size,
                              hipStream_t stream) {
    const float* x = (const float*)d_in[0];
    const int* eb = (const int*)d_in[1];
    const int E = NEDGES;
    const int N = NNODES;

    const float* w1[3] = {(const float*)d_in[2], (const float*)d_in[6], (const float*)d_in[10]};
    const float* b1[3] = {(const float*)d_in[3], (const float*)d_in[7], (const float*)d_in[11]};
    const float* w2[3] = {(const float*)d_in[4], (const float*)d_in[8], (const float*)d_in[12]};
    const float* b2[3] = {(const float*)d_in[5], (const float*)d_in[9], (const float*)d_in[13]};

    // workspace layout
    char* ws = (char*)d_ws;
    size_t off = 0;
    auto alloc = [&](size_t bytes) {
        void* p = ws + off;
        off += (bytes + 255) & ~(size_t)255;
        return p;
    };
    int* flag   = (int*)alloc(4);
    int* cnt    = (int*)alloc((size_t)N * 4);
    int* offs   = (int*)alloc((size_t)(N + 1) * 4);
    int* cursor = (int*)alloc((size_t)N * 4);
    int* srcs   = (int*)alloc((size_t)E * 4);
    float* zbuf = (float*)alloc((size_t)N * DH * 4);
    float* hbuf = (float*)alloc((size_t)N * DH * 4);
    float* tbuf = (float*)alloc((size_t)N * DH * 4);
    (void)ws_size; (void)n_in; (void)out_size; (void)in_sizes;

    // --- CSR build
    detect_i32_kernel<<<1, 256, 0, stream>>>(eb, 1024, flag);
    zero_i_kernel<<<(N + 255) / 256, 256, 0, stream>>>(cnt, N);
    hist_kernel<<<(E + 255) / 256, 256, 0, stream>>>(eb, flag, cnt, E);
    scan_kernel<<<1, 1024, 0, stream>>>(cnt, offs, cursor, N);
    scatter_kernel<<<(E + 255) / 256, 256, 0, stream>>>(eb, flag, cursor, srcs, E);

    dim3 gemm_grid((N + 63) / 64, DH / 64);

    // --- layer 0 (D_in = 128)
    agg_add_kernel<128><<<(N + 3) / 4, 256, 0, stream>>>(x, srcs, offs, hbuf, N);
    gemm_bias_relu_kernel<<<gemm_grid, 256, 0, stream>>>(hbuf, w1[0], b1[0], tbuf, N, DH, DIN);
    gemm_bias_relu_kernel<<<gemm_grid, 256, 0, stream>>>(tbuf, w2[0], b2[0], zbuf, N, DH, DH);

    // --- layer 1
    agg_add_kernel<256><<<(N + 3) / 4, 256, 0, stream>>>(zbuf, srcs, offs, hbuf, N);
    gemm_bias_relu_kernel<<<gemm_grid, 256, 0, stream>>>(hbuf, w1[1], b1[1], tbuf, N, DH, DH);
    gemm_bias_relu_kernel<<<gemm_grid, 256, 0, stream>>>(tbuf, w2[1], b2[1], zbuf, N, DH, DH);

    // --- layer 2 (final output to d_out)
    agg_add_kernel<256><<<(N + 3) / 4, 256, 0, stream>>>(zbuf, srcs, offs, hbuf, N);
    gemm_bias_relu_kernel<<<gemm_grid, 256, 0, stream>>>(hbuf, w1[2], b1[2], tbuf, N, DH, DH);
    gemm_bias_relu_kernel<<<gemm_grid, 256, 0, stream>>>(tbuf, w2[2], b2[2], (float*)d_out, N, DH, DH);
}

// Round 2
// 313.828 us; speedup vs baseline: 1.1250x; 1.1250x over previous
//
#include <hip/hip_runtime.h>
#include <hip/hip_bf16.h>
#include <cstdint>

// ---------------------------------------------------------------------------
// GNN encoder: 3 x { agg = segment_sum(z[src], dst); h = z + agg;
//                    t = relu(h@w1+b1); z = relu(t@w2+b2) }
// CSR build per call (no float atomics), then:
//   agg: feature-SLICED gather. slice = blockIdx & 7 -> bound to one XCD via
//   round-robin block->XCD mapping; per-XCD working set = N * 128B = 1.28 MB
//   which is L2-resident (4 MB/XCD). Turns the 327 MB gather into L2 hits.
// ---------------------------------------------------------------------------

#define NNODES 10000
#define NEDGES 320000
#define DIN 128
#define DH 256

// --- edge_index storage detection (int64 vs int32), deterministic each call.
__global__ void detect_i32_kernel(const int* __restrict__ eb, int nsample, int* __restrict__ flag) {
    __shared__ int any;
    if (threadIdx.x == 0) any = 0;
    __syncthreads();
    for (int i = threadIdx.x; i < nsample; i += blockDim.x)
        if (eb[2 * i + 1] != 0) any = 1;
    __syncthreads();
    if (threadIdx.x == 0) flag[0] = any;   // 1 => int32 storage, 0 => int64
}

__device__ __forceinline__ int eload(const int* __restrict__ eb, int is32, long logical_idx) {
    return is32 ? eb[logical_idx] : eb[2 * logical_idx]; // little-endian low word
}

__global__ void zero_i_kernel(int* __restrict__ p, int n) {
    int i = blockIdx.x * blockDim.x + threadIdx.x;
    if (i < n) p[i] = 0;
}

__global__ void hist_kernel(const int* __restrict__ eb, const int* __restrict__ flag,
                            int* __restrict__ cnt, int E) {
    int i = blockIdx.x * blockDim.x + threadIdx.x;
    if (i >= E) return;
    int is32 = flag[0];
    int d = eload(eb, is32, (long)E + i);
    atomicAdd(&cnt[d], 1);
}

// single-block exclusive scan over N counts -> offs[N+1], cursor copy
__global__ __launch_bounds__(1024) void scan_kernel(const int* __restrict__ cnt,
                                                    int* __restrict__ offs,
                                                    int* __restrict__ cursor, int n) {
    __shared__ int sums[1024];
    int tid = threadIdx.x;
    int per = (n + 1023) / 1024;          // 10 for n=10000
    int beg = tid * per;
    int local[16];
    int s = 0;
    for (int i = 0; i < per; ++i) {
        int idx = beg + i;
        int v = (idx < n) ? cnt[idx] : 0;
        local[i] = s;
        s += v;
    }
    sums[tid] = s;
    __syncthreads();
    for (int d = 1; d < 1024; d <<= 1) {
        int y = (tid >= d) ? sums[tid - d] : 0;
        __syncthreads();
        sums[tid] += y;
        __syncthreads();
    }
    int base = sums[tid] - s;             // exclusive prefix of this thread's chunk
    for (int i = 0; i < per; ++i) {
        int idx = beg + i;
        if (idx < n) {
            int v = base + local[i];
            offs[idx] = v;
            cursor[idx] = v;
        }
    }
    if (tid == 1023) offs[n] = sums[1023];
}

__global__ void scatter_kernel(const int* __restrict__ eb, const int* __restrict__ flag,
                               int* __restrict__ cursor, int* __restrict__ srcs, int E) {
    int i = blockIdx.x * blockDim.x + threadIdx.x;
    if (i >= E) return;
    int is32 = flag[0];
    int s = eload(eb, is32, (long)i);
    int d = eload(eb, is32, (long)E + i);
    int pos = atomicAdd(&cursor[d], 1);
    srcs[pos] = s;
}

// --- sliced aggregation: h[i] = z[i] + sum_{e in CSR[i]} z[src_e].
// 8 feature slices of D/8 floats; slice = blockIdx & 7 (XCD-bound). Each
// node-slice handled by LPN lanes doing one float4 each.
template <int D>
__global__ __launch_bounds__(256) void agg_add_sliced_kernel(const float* __restrict__ z,
                                                             const int* __restrict__ srcs,
                                                             const int* __restrict__ offs,
                                                             float* __restrict__ h, int n) {
    constexpr int SLICE_F = D / 8;     // floats per slice (256->32, 128->16)
    constexpr int LPN = SLICE_F / 4;   // lanes per node-slice (float4 each)
    constexpr int NPB = 256 / LPN;     // nodes per block (256->32, 128->64)
    int bid = blockIdx.x;
    int slice = bid & 7;
    int ng = bid >> 3;
    int t = threadIdx.x;
    int node = ng * NPB + t / LPN;
    if (node >= n) return;
    int li = t % LPN;
    int colv = slice * LPN + li;       // float4 column index within row
    const float4* zb = reinterpret_cast<const float4*>(z);
    int beg = offs[node], end = offs[node + 1];
    float4 acc = zb[(size_t)node * (D / 4) + colv];   // residual z term
    for (int e = beg; e < end; ++e) {
        int s = srcs[e];
        float4 v = zb[(size_t)s * (D / 4) + colv];
        acc.x += v.x; acc.y += v.y; acc.z += v.z; acc.w += v.w;
    }
    reinterpret_cast<float4*>(h)[(size_t)node * (D / 4) + colv] = acc;
}

// --- fp32 GEMM C = relu(A @ W + bias); A: MxK, W: KxNc (row-major), C: MxNc.
// 64x64 tile, BK=16, 256 threads, 4x4 microtile.
__global__ __launch_bounds__(256) void gemm_bias_relu_kernel(const float* __restrict__ A,
                                                             const float* __restrict__ W,
                                                             const float* __restrict__ bias,
                                                             float* __restrict__ C,
                                                             int M, int Nc, int K) {
    __shared__ float As[64][16];
    __shared__ float Ws[16][64];
    int tid = threadIdx.x;
    int tx = tid & 15, ty = tid >> 4;
    int m0 = blockIdx.x * 64;
    int n0 = blockIdx.y * 64;
    float acc[4][4] = {};
    for (int k0 = 0; k0 < K; k0 += 16) {
        { // stage A tile (64x16)
            int r = tid >> 2;
            int c4 = (tid & 3) * 4;
            int gr = m0 + r;
            float4 v = make_float4(0.f, 0.f, 0.f, 0.f);
            if (gr < M) v = *reinterpret_cast<const float4*>(&A[(size_t)gr * K + k0 + c4]);
            As[r][c4 + 0] = v.x; As[r][c4 + 1] = v.y; As[r][c4 + 2] = v.z; As[r][c4 + 3] = v.w;
        }
        { // stage W tile (16x64)
            int rw = tid >> 4;
            int cw = (tid & 15) * 4;
            float4 wv = *reinterpret_cast<const float4*>(&W[(size_t)(k0 + rw) * Nc + n0 + cw]);
            Ws[rw][cw + 0] = wv.x; Ws[rw][cw + 1] = wv.y; Ws[rw][cw + 2] = wv.z; Ws[rw][cw + 3] = wv.w;
        }
        __syncthreads();
#pragma unroll
        for (int kk = 0; kk < 16; ++kk) {
            float a[4], b[4];
#pragma unroll
            for (int i = 0; i < 4; ++i) a[i] = As[ty * 4 + i][kk];
#pragma unroll
            for (int j = 0; j < 4; ++j) b[j] = Ws[kk][tx * 4 + j];
#pragma unroll
            for (int i = 0; i < 4; ++i)
#pragma unroll
                for (int j = 0; j < 4; ++j) acc[i][j] += a[i] * b[j];
        }
        __syncthreads();
    }
    int gc = n0 + tx * 4;
    float4 bv = *reinterpret_cast<const float4*>(&bias[gc]);
#pragma unroll
    for (int i = 0; i < 4; ++i) {
        int gr = m0 + ty * 4 + i;
        if (gr >= M) break;
        float4 o;
        o.x = fmaxf(acc[i][0] + bv.x, 0.f);
        o.y = fmaxf(acc[i][1] + bv.y, 0.f);
        o.z = fmaxf(acc[i][2] + bv.z, 0.f);
        o.w = fmaxf(acc[i][3] + bv.w, 0.f);
        *reinterpret_cast<float4*>(&C[(size_t)gr * Nc + gc]) = o;
    }
}

extern "C" void kernel_launch(void* const* d_in, const int* in_sizes, int n_in,
                              void* d_out, int out_size, void* d_ws, size_t ws_size,
                              hipStream_t stream) {
    const float* x = (const float*)d_in[0];
    const int* eb = (const int*)d_in[1];
    const int E = NEDGES;
    const int N = NNODES;

    const float* w1[3] = {(const float*)d_in[2], (const float*)d_in[6], (const float*)d_in[10]};
    const float* b1[3] = {(const float*)d_in[3], (const float*)d_in[7], (const float*)d_in[11]};
    const float* w2[3] = {(const float*)d_in[4], (const float*)d_in[8], (const float*)d_in[12]};
    const float* b2[3] = {(const float*)d_in[5], (const float*)d_in[9], (const float*)d_in[13]};

    // workspace layout
    char* ws = (char*)d_ws;
    size_t off = 0;
    auto alloc = [&](size_t bytes) {
        void* p = ws + off;
        off += (bytes + 255) & ~(size_t)255;
        return p;
    };
    int* flag   = (int*)alloc(4);
    int* cnt    = (int*)alloc((size_t)N * 4);
    int* offs   = (int*)alloc((size_t)(N + 1) * 4);
    int* cursor = (int*)alloc((size_t)N * 4);
    int* srcs   = (int*)alloc((size_t)E * 4);
    float* zbuf = (float*)alloc((size_t)N * DH * 4);
    float* hbuf = (float*)alloc((size_t)N * DH * 4);
    float* tbuf = (float*)alloc((size_t)N * DH * 4);
    (void)ws_size; (void)n_in; (void)out_size; (void)in_sizes;

    // --- CSR build
    detect_i32_kernel<<<1, 256, 0, stream>>>(eb, 1024, flag);
    zero_i_kernel<<<(N + 255) / 256, 256, 0, stream>>>(cnt, N);
    hist_kernel<<<(E + 255) / 256, 256, 0, stream>>>(eb, flag, cnt, E);
    scan_kernel<<<1, 1024, 0, stream>>>(cnt, offs, cursor, N);
    scatter_kernel<<<(E + 255) / 256, 256, 0, stream>>>(eb, flag, cursor, srcs, E);

    dim3 gemm_grid((N + 63) / 64, DH / 64);

    // sliced agg grids: 8 slices * ceil(N / nodes_per_block)
    int agg_blocks_256 = ((N + 31) / 32) * 8;   // D=256: 32 nodes/block
    int agg_blocks_128 = ((N + 63) / 64) * 8;   // D=128: 64 nodes/block

    // --- layer 0 (D_in = 128)
    agg_add_sliced_kernel<128><<<agg_blocks_128, 256, 0, stream>>>(x, srcs, offs, hbuf, N);
    gemm_bias_relu_kernel<<<gemm_grid, 256, 0, stream>>>(hbuf, w1[0], b1[0], tbuf, N, DH, DIN);
    gemm_bias_relu_kernel<<<gemm_grid, 256, 0, stream>>>(tbuf, w2[0], b2[0], zbuf, N, DH, DH);

    // --- layer 1
    agg_add_sliced_kernel<256><<<agg_blocks_256, 256, 0, stream>>>(zbuf, srcs, offs, hbuf, N);
    gemm_bias_relu_kernel<<<gemm_grid, 256, 0, stream>>>(hbuf, w1[1], b1[1], tbuf, N, DH, DH);
    gemm_bias_relu_kernel<<<gemm_grid, 256, 0, stream>>>(tbuf, w2[1], b2[1], zbuf, N, DH, DH);

    // --- layer 2 (final output to d_out)
    agg_add_sliced_kernel<256><<<agg_blocks_256, 256, 0, stream>>>(zbuf, srcs, offs, hbuf, N);
    gemm_bias_relu_kernel<<<gemm_grid, 256, 0, stream>>>(hbuf, w1[2], b1[2], tbuf, N, DH, DH);
    gemm_bias_relu_kernel<<<gemm_grid, 256, 0, stream>>>(tbuf, w2[2], b2[2], (float*)d_out, N, DH, DH);
}

// Round 3
// 224.471 us; speedup vs baseline: 1.5728x; 1.3981x over previous
//
#include <hip/hip_runtime.h>
#include <hip/hip_bf16.h>
#include <cstdint>

// ---------------------------------------------------------------------------
// GNN encoder: 3 x { agg = segment_sum(z[src], dst); h = z + agg;
//                    t = relu(h@w1+b1); z = relu(t@w2+b2) }
// CSR build per call (no float atomics). Sliced gather agg (XCD/L2 locality).
// GEMMs via MFMA bf16 16x16x32: agg emits h in bf16, weights converted +
// transposed to bf16 once per call, GEMM1 -> t (bf16), GEMM2 -> z (fp32).
// ---------------------------------------------------------------------------

#define NNODES 10000
#define NEDGES 320000
#define DIN 128
#define DH 256

typedef __bf16 bf16x8 __attribute__((ext_vector_type(8)));
typedef unsigned short ushort8v __attribute__((ext_vector_type(8)));
typedef unsigned short ushort4v __attribute__((ext_vector_type(4)));
typedef float f32x4 __attribute__((ext_vector_type(4)));

__device__ __forceinline__ unsigned short f2bf(float f) {
    unsigned int u = __float_as_uint(f);
    unsigned int r = u + 0x7fffu + ((u >> 16) & 1u);   // round-to-nearest-even
    return (unsigned short)(r >> 16);
}

// --- edge_index storage detection (int64 vs int32), deterministic each call.
__global__ void detect_i32_kernel(const int* __restrict__ eb, int nsample, int* __restrict__ flag) {
    __shared__ int any;
    if (threadIdx.x == 0) any = 0;
    __syncthreads();
    for (int i = threadIdx.x; i < nsample; i += blockDim.x)
        if (eb[2 * i + 1] != 0) any = 1;
    __syncthreads();
    if (threadIdx.x == 0) flag[0] = any;   // 1 => int32 storage, 0 => int64
}

__device__ __forceinline__ int eload(const int* __restrict__ eb, int is32, long logical_idx) {
    return is32 ? eb[logical_idx] : eb[2 * logical_idx]; // little-endian low word
}

__global__ void zero_i_kernel(int* __restrict__ p, int n) {
    int i = blockIdx.x * blockDim.x + threadIdx.x;
    if (i < n) p[i] = 0;
}

__global__ void hist_kernel(const int* __restrict__ eb, const int* __restrict__ flag,
                            int* __restrict__ cnt, int E) {
    int i = blockIdx.x * blockDim.x + threadIdx.x;
    if (i >= E) return;
    int is32 = flag[0];
    int d = eload(eb, is32, (long)E + i);
    atomicAdd(&cnt[d], 1);
}

// single-block exclusive scan over N counts -> offs[N+1], cursor copy
__global__ __launch_bounds__(1024) void scan_kernel(const int* __restrict__ cnt,
                                                    int* __restrict__ offs,
                                                    int* __restrict__ cursor, int n) {
    __shared__ int sums[1024];
    int tid = threadIdx.x;
    int per = (n + 1023) / 1024;          // 10 for n=10000
    int beg = tid * per;
    int local[16];
    int s = 0;
    for (int i = 0; i < per; ++i) {
        int idx = beg + i;
        int v = (idx < n) ? cnt[idx] : 0;
        local[i] = s;
        s += v;
    }
    sums[tid] = s;
    __syncthreads();
    for (int d = 1; d < 1024; d <<= 1) {
        int y = (tid >= d) ? sums[tid - d] : 0;
        __syncthreads();
        sums[tid] += y;
        __syncthreads();
    }
    int base = sums[tid] - s;             // exclusive prefix of this thread's chunk
    for (int i = 0; i < per; ++i) {
        int idx = beg + i;
        if (idx < n) {
            int v = base + local[i];
            offs[idx] = v;
            cursor[idx] = v;
        }
    }
    if (tid == 1023) offs[n] = sums[1023];
}

__global__ void scatter_kernel(const int* __restrict__ eb, const int* __restrict__ flag,
                               int* __restrict__ cursor, int* __restrict__ srcs, int E) {
    int i = blockIdx.x * blockDim.x + threadIdx.x;
    if (i >= E) return;
    int is32 = flag[0];
    int s = eload(eb, is32, (long)i);
    int d = eload(eb, is32, (long)E + i);
    int pos = atomicAdd(&cursor[d], 1);
    srcs[pos] = s;
}

// --- weight convert + transpose: src fp32 [K][256] -> dst bf16 [256][K]
struct WconvArgs {
    const float* src[6];
    unsigned short* dst[6];
    int kbits[6];   // log2(K): 7 for w1_0, 8 otherwise
};
__global__ void wconv_kernel(WconvArgs a) {
    int m = blockIdx.y;
    int kb = a.kbits[m];
    int K = 1 << kb;
    int total = K << 8;   // K * 256
    int idx = blockIdx.x * 256 + threadIdx.x;
    if (idx >= total) return;
    int nn = idx >> kb;         // output row (col of src)
    int kk = idx & (K - 1);     // output col (row of src)
    a.dst[m][idx] = f2bf(a.src[m][(size_t)kk * 256 + nn]);
}

// --- sliced aggregation: h[i] = z[i] + sum_{e in CSR[i]} z[src_e], bf16 out.
// 8 feature slices; slice = blockIdx & 7 (XCD-bound via round-robin mapping).
template <int D>
__global__ __launch_bounds__(256) void agg_add_sliced_kernel(const float* __restrict__ z,
                                                             const int* __restrict__ srcs,
                                                             const int* __restrict__ offs,
                                                             unsigned short* __restrict__ h, int n) {
    constexpr int SLICE_F = D / 8;     // floats per slice (256->32, 128->16)
    constexpr int LPN = SLICE_F / 4;   // lanes per node-slice (float4 each)
    constexpr int NPB = 256 / LPN;     // nodes per block
    int bid = blockIdx.x;
    int slice = bid & 7;
    int ng = bid >> 3;
    int t = threadIdx.x;
    int node = ng * NPB + t / LPN;
    if (node >= n) return;
    int li = t % LPN;
    int colv = slice * LPN + li;       // float4 column index within row
    const float4* zb = reinterpret_cast<const float4*>(z);
    int beg = offs[node], end = offs[node + 1];
    float4 acc = zb[(size_t)node * (D / 4) + colv];   // residual z term
    for (int e = beg; e < end; ++e) {
        int s = srcs[e];
        float4 v = zb[(size_t)s * (D / 4) + colv];
        acc.x += v.x; acc.y += v.y; acc.z += v.z; acc.w += v.w;
    }
    ushort4v o = {f2bf(acc.x), f2bf(acc.y), f2bf(acc.z), f2bf(acc.w)};
    *reinterpret_cast<ushort4v*>(&h[(size_t)node * D + colv * 4]) = o;
}

// --- MFMA GEMM: C = relu(A @ W + bias). A: MxK bf16 row-major,
// Wt: NcxK bf16 (W transposed), bias fp32, C bf16 or fp32.
// 64x64 tile, 4 waves (wave w = rows w*16..w*16+15), BK=32.
// LDS fragment-order [kc][row][8] so all ds_reads are conflict-free b128.
template <int OUT_BF16>
__global__ __launch_bounds__(256) void gemm_mfma_kernel(const unsigned short* __restrict__ A,
                                                        const unsigned short* __restrict__ Wt,
                                                        const float* __restrict__ bias,
                                                        void* __restrict__ C,
                                                        int M, int Nc, int K) {
    __shared__ unsigned short As[4][64][8];   // [kc][row][j]
    __shared__ unsigned short Bs[4][64][8];   // [kc][col][j]
    int tid = threadIdx.x;
    int wave = tid >> 6, lane = tid & 63;
    int m0 = blockIdx.x * 64, n0 = blockIdx.y * 64;
    f32x4 acc[4];
#pragma unroll
    for (int c = 0; c < 4; ++c) acc[c] = (f32x4){0.f, 0.f, 0.f, 0.f};

    int sr = tid >> 2;        // staging row/col 0..63
    int sc = tid & 3;         // staging k-chunk 0..3
    int fr = lane & 15;       // fragment row/col
    int kc = lane >> 4;       // fragment k-chunk

    for (int k0 = 0; k0 < K; k0 += 32) {
        // stage A tile (64 rows x 32 k) -> As[kc][row][8]
        int gr = m0 + sr;
        ushort8v av = {0, 0, 0, 0, 0, 0, 0, 0};
        if (gr < M) av = *reinterpret_cast<const ushort8v*>(&A[(size_t)gr * K + k0 + sc * 8]);
        *reinterpret_cast<ushort8v*>(&As[sc][sr][0]) = av;
        // stage B tile (64 cols x 32 k) -> Bs[kc][col][8]
        ushort8v bv = *reinterpret_cast<const ushort8v*>(&Wt[(size_t)(n0 + sr) * K + k0 + sc * 8]);
        *reinterpret_cast<ushort8v*>(&Bs[sc][sr][0]) = bv;
        __syncthreads();

        bf16x8 af = __builtin_bit_cast(bf16x8,
            *reinterpret_cast<const ushort8v*>(&As[kc][wave * 16 + fr][0]));
#pragma unroll
        for (int c = 0; c < 4; ++c) {
            bf16x8 bf = __builtin_bit_cast(bf16x8,
                *reinterpret_cast<const ushort8v*>(&Bs[kc][c * 16 + fr][0]));
            acc[c] = __builtin_amdgcn_mfma_f32_16x16x32_bf16(af, bf, acc[c], 0, 0, 0);
        }
        __syncthreads();
    }

    // epilogue: D[row=(lane>>4)*4+j][col=lane&15] per 16x16 fragment
    int rg = lane >> 4;
#pragma unroll
    for (int c = 0; c < 4; ++c) {
        int col = n0 + c * 16 + fr;
        float b = bias[col];
#pragma unroll
        for (int j = 0; j < 4; ++j) {
            int row = m0 + wave * 16 + rg * 4 + j;
            if (row < M) {
                float v = fmaxf(acc[c][j] + b, 0.f);
                if (OUT_BF16)
                    ((unsigned short*)C)[(size_t)row * Nc + col] = f2bf(v);
                else
                    ((float*)C)[(size_t)row * Nc + col] = v;
            }
        }
    }
}

extern "C" void kernel_launch(void* const* d_in, const int* in_sizes, int n_in,
                              void* d_out, int out_size, void* d_ws, size_t ws_size,
                              hipStream_t stream) {
    const float* x = (const float*)d_in[0];
    const int* eb = (const int*)d_in[1];
    const int E = NEDGES;
    const int N = NNODES;

    const float* w1[3] = {(const float*)d_in[2], (const float*)d_in[6], (const float*)d_in[10]};
    const float* b1[3] = {(const float*)d_in[3], (const float*)d_in[7], (const float*)d_in[11]};
    const float* w2[3] = {(const float*)d_in[4], (const float*)d_in[8], (const float*)d_in[12]};
    const float* b2[3] = {(const float*)d_in[5], (const float*)d_in[9], (const float*)d_in[13]};

    // workspace layout
    char* ws = (char*)d_ws;
    size_t off = 0;
    auto alloc = [&](size_t bytes) {
        void* p = ws + off;
        off += (bytes + 255) & ~(size_t)255;
        return p;
    };
    int* flag   = (int*)alloc(4);
    int* cnt    = (int*)alloc((size_t)N * 4);
    int* offs   = (int*)alloc((size_t)(N + 1) * 4);
    int* cursor = (int*)alloc((size_t)N * 4);
    int* srcs   = (int*)alloc((size_t)E * 4);
    float* zbuf = (float*)alloc((size_t)N * DH * 4);
    unsigned short* hbuf = (unsigned short*)alloc((size_t)N * DH * 2);
    unsigned short* tbuf = (unsigned short*)alloc((size_t)N * DH * 2);
    unsigned short* wt[6];
    wt[0] = (unsigned short*)alloc((size_t)DIN * DH * 2);          // w1_0^T: 256x128
    for (int i = 1; i < 6; ++i) wt[i] = (unsigned short*)alloc((size_t)DH * DH * 2);
    (void)ws_size; (void)n_in; (void)out_size; (void)in_sizes;

    // --- CSR build
    detect_i32_kernel<<<1, 256, 0, stream>>>(eb, 1024, flag);
    zero_i_kernel<<<(N + 255) / 256, 256, 0, stream>>>(cnt, N);
    hist_kernel<<<(E + 255) / 256, 256, 0, stream>>>(eb, flag, cnt, E);
    scan_kernel<<<1, 1024, 0, stream>>>(cnt, offs, cursor, N);
    scatter_kernel<<<(E + 255) / 256, 256, 0, stream>>>(eb, flag, cursor, srcs, E);

    // --- weight convert + transpose (all 6 at once)
    WconvArgs wa;
    wa.src[0] = w1[0]; wa.src[1] = w2[0]; wa.src[2] = w1[1];
    wa.src[3] = w2[1]; wa.src[4] = w1[2]; wa.src[5] = w2[2];
    for (int i = 0; i < 6; ++i) wa.dst[i] = wt[i];
    wa.kbits[0] = 7;
    for (int i = 1; i < 6; ++i) wa.kbits[i] = 8;
    wconv_kernel<<<dim3(256, 6), 256, 0, stream>>>(wa);

    dim3 gemm_grid((N + 63) / 64, DH / 64);
    int agg_blocks_256 = ((N + 31) / 32) * 8;   // D=256: 32 nodes/block
    int agg_blocks_128 = ((N + 63) / 64) * 8;   // D=128: 64 nodes/block

    // --- layer 0 (D_in = 128)
    agg_add_sliced_kernel<128><<<agg_blocks_128, 256, 0, stream>>>(x, srcs, offs, hbuf, N);
    gemm_mfma_kernel<1><<<gemm_grid, 256, 0, stream>>>(hbuf, wt[0], b1[0], tbuf, N, DH, DIN);
    gemm_mfma_kernel<0><<<gemm_grid, 256, 0, stream>>>(tbuf, wt[1], b2[0], zbuf, N, DH, DH);

    // --- layer 1
    agg_add_sliced_kernel<256><<<agg_blocks_256, 256, 0, stream>>>(zbuf, srcs, offs, hbuf, N);
    gemm_mfma_kernel<1><<<gemm_grid, 256, 0, stream>>>(hbuf, wt[2], b1[1], tbuf, N, DH, DH);
    gemm_mfma_kernel<0><<<gemm_grid, 256, 0, stream>>>(tbuf, wt[3], b2[1], zbuf, N, DH, DH);

    // --- layer 2 (final output to d_out)
    agg_add_sliced_kernel<256><<<agg_blocks_256, 256, 0, stream>>>(zbuf, srcs, offs, hbuf, N);
    gemm_mfma_kernel<1><<<gemm_grid, 256, 0, stream>>>(hbuf, wt[4], b1[2], tbuf, N, DH, DH);
    gemm_mfma_kernel<0><<<gemm_grid, 256, 0, stream>>>(tbuf, wt[5], b2[2], (float*)d_out, N, DH, DH);
}

// Round 4
// 186.375 us; speedup vs baseline: 1.8943x; 1.2044x over previous
//
#include <hip/hip_runtime.h>
#include <hip/hip_bf16.h>
#include <cstdint>

// ---------------------------------------------------------------------------
// GNN encoder: 3 x { agg = segment_sum(z[src], dst); h = z + agg;
//                    t = relu(h@w1+b1); z = relu(t@w2+b2) }
// CSR build per call (no float atomics). z kept in bf16 between layers.
// agg: feature-sliced gather (slice bound to one XCD -> L2-resident) with
// 4-way edge unroll (4 independent load chains) to beat L2 latency.
// GEMMs: MFMA bf16 16x16x32, weights converted+transposed per call.
// ---------------------------------------------------------------------------

#define NNODES 10000
#define NEDGES 320000
#define DIN 128
#define DH 256

typedef __bf16 bf16x8 __attribute__((ext_vector_type(8)));
typedef unsigned short ushort8v __attribute__((ext_vector_type(8)));
typedef unsigned short ushort4v __attribute__((ext_vector_type(4)));
typedef float f32x4 __attribute__((ext_vector_type(4)));

__device__ __forceinline__ unsigned short f2bf(float f) {
    unsigned int u = __float_as_uint(f);
    unsigned int r = u + 0x7fffu + ((u >> 16) & 1u);   // round-to-nearest-even
    return (unsigned short)(r >> 16);
}
__device__ __forceinline__ float bf2f(unsigned short u) {
    return __uint_as_float(((unsigned int)u) << 16);
}

// --- edge_index storage detection (int64 vs int32), deterministic each call.
__global__ void detect_i32_kernel(const int* __restrict__ eb, int nsample, int* __restrict__ flag) {
    __shared__ int any;
    if (threadIdx.x == 0) any = 0;
    __syncthreads();
    for (int i = threadIdx.x; i < nsample; i += blockDim.x)
        if (eb[2 * i + 1] != 0) any = 1;
    __syncthreads();
    if (threadIdx.x == 0) flag[0] = any;   // 1 => int32 storage, 0 => int64
}

__device__ __forceinline__ int eload(const int* __restrict__ eb, int is32, long logical_idx) {
    return is32 ? eb[logical_idx] : eb[2 * logical_idx]; // little-endian low word
}

__global__ void zero_i_kernel(int* __restrict__ p, int n) {
    int i = blockIdx.x * blockDim.x + threadIdx.x;
    if (i < n) p[i] = 0;
}

__global__ void hist_kernel(const int* __restrict__ eb, const int* __restrict__ flag,
                            int* __restrict__ cnt, int E) {
    int i = blockIdx.x * blockDim.x + threadIdx.x;
    if (i >= E) return;
    int is32 = flag[0];
    int d = eload(eb, is32, (long)E + i);
    atomicAdd(&cnt[d], 1);
}

// single-block exclusive scan over N counts -> offs[N+1], cursor copy
__global__ __launch_bounds__(1024) void scan_kernel(const int* __restrict__ cnt,
                                                    int* __restrict__ offs,
                                                    int* __restrict__ cursor, int n) {
    __shared__ int sums[1024];
    int tid = threadIdx.x;
    int per = (n + 1023) / 1024;          // 10 for n=10000
    int beg = tid * per;
    int local[16];
    int s = 0;
    for (int i = 0; i < per; ++i) {
        int idx = beg + i;
        int v = (idx < n) ? cnt[idx] : 0;
        local[i] = s;
        s += v;
    }
    sums[tid] = s;
    __syncthreads();
    for (int d = 1; d < 1024; d <<= 1) {
        int y = (tid >= d) ? sums[tid - d] : 0;
        __syncthreads();
        sums[tid] += y;
        __syncthreads();
    }
    int base = sums[tid] - s;             // exclusive prefix of this thread's chunk
    for (int i = 0; i < per; ++i) {
        int idx = beg + i;
        if (idx < n) {
            int v = base + local[i];
            offs[idx] = v;
            cursor[idx] = v;
        }
    }
    if (tid == 1023) offs[n] = sums[1023];
}

__global__ void scatter_kernel(const int* __restrict__ eb, const int* __restrict__ flag,
                               int* __restrict__ cursor, int* __restrict__ srcs, int E) {
    int i = blockIdx.x * blockDim.x + threadIdx.x;
    if (i >= E) return;
    int is32 = flag[0];
    int s = eload(eb, is32, (long)i);
    int d = eload(eb, is32, (long)E + i);
    int pos = atomicAdd(&cursor[d], 1);
    srcs[pos] = s;
}

// --- weight convert + transpose: src fp32 [K][256] -> dst bf16 [256][K]
struct WconvArgs {
    const float* src[6];
    unsigned short* dst[6];
    int kbits[6];   // log2(K): 7 for w1_0, 8 otherwise
};
__global__ void wconv_kernel(WconvArgs a) {
    int m = blockIdx.y;
    int kb = a.kbits[m];
    int K = 1 << kb;
    int total = K << 8;   // K * 256
    int idx = blockIdx.x * 256 + threadIdx.x;
    if (idx >= total) return;
    int nn = idx >> kb;         // output row (col of src)
    int kk = idx & (K - 1);     // output col (row of src)
    a.dst[m][idx] = f2bf(a.src[m][(size_t)kk * 256 + nn]);
}

// --- x fp32 -> bf16 (vectorized: one float4 -> ushort4 per thread)
__global__ void xconv_kernel(const float* __restrict__ x, unsigned short* __restrict__ xb, int total4) {
    int i = blockIdx.x * blockDim.x + threadIdx.x;
    if (i >= total4) return;
    float4 v = reinterpret_cast<const float4*>(x)[i];
    ushort4v o = {f2bf(v.x), f2bf(v.y), f2bf(v.z), f2bf(v.w)};
    reinterpret_cast<ushort4v*>(xb)[i] = o;
}

// --- sliced bf16 aggregation: h[i] = z[i] + sum_{e in CSR[i]} z[src_e].
// NSLICE feature slices; slice = bid & (NSLICE-1). Round-robin block->XCD
// gives each XCD exactly one slice (working set N * 64B = 0.64 MB, L2-hot).
// 4-way edge unroll: 4 independent gather chains per lane.
template <int D>
__global__ __launch_bounds__(256) void agg_add_sliced_kernel(const unsigned short* __restrict__ z,
                                                             const int* __restrict__ srcs,
                                                             const int* __restrict__ offs,
                                                             unsigned short* __restrict__ h, int n) {
    constexpr int NSLICE = (D == 256) ? 8 : 4;
    constexpr int SLICE_E = D / NSLICE;   // 32 elems per slice
    constexpr int LPN = SLICE_E / 8;      // 4 lanes per node (ushort8 each)
    constexpr int NPB = 256 / LPN;        // 64 nodes per block
    int bid = blockIdx.x;
    int slice = bid & (NSLICE - 1);
    int ng = bid / NSLICE;
    int t = threadIdx.x;
    int node = ng * NPB + t / LPN;
    if (node >= n) return;
    int li = t % LPN;
    int col8 = slice * LPN + li;          // ushort8 column index within row
    const ushort8v* zb = reinterpret_cast<const ushort8v*>(z);
    const int ld8 = D / 8;
    int beg = offs[node], end = offs[node + 1];

    float a0[8] = {}, a1[8] = {}, a2[8] = {}, a3[8] = {};
    int e = beg;
    for (; e + 4 <= end; e += 4) {
        int s0 = srcs[e], s1 = srcs[e + 1], s2 = srcs[e + 2], s3 = srcs[e + 3];
        ushort8v v0 = zb[(size_t)s0 * ld8 + col8];
        ushort8v v1 = zb[(size_t)s1 * ld8 + col8];
        ushort8v v2 = zb[(size_t)s2 * ld8 + col8];
        ushort8v v3 = zb[(size_t)s3 * ld8 + col8];
#pragma unroll
        for (int j = 0; j < 8; ++j) {
            a0[j] += bf2f(v0[j]);
            a1[j] += bf2f(v1[j]);
            a2[j] += bf2f(v2[j]);
            a3[j] += bf2f(v3[j]);
        }
    }
    for (; e < end; ++e) {
        ushort8v v = zb[(size_t)srcs[e] * ld8 + col8];
#pragma unroll
        for (int j = 0; j < 8; ++j) a0[j] += bf2f(v[j]);
    }
    ushort8v zr = zb[(size_t)node * ld8 + col8];   // residual z term
    ushort8v o;
#pragma unroll
    for (int j = 0; j < 8; ++j) {
        float v = a0[j] + a1[j] + a2[j] + a3[j] + bf2f(zr[j]);
        o[j] = f2bf(v);
    }
    reinterpret_cast<ushort8v*>(h)[(size_t)node * ld8 + col8] = o;
}

// --- MFMA GEMM: C = relu(A @ W + bias). A: MxK bf16 row-major,
// Wt: NcxK bf16 (W transposed), bias fp32, C bf16 or fp32.
// 64x64 tile, 4 waves (wave w = rows w*16..w*16+15), BK=32.
// LDS fragment-order [kc][row][8] so all ds_reads are conflict-free b128.
template <int OUT_BF16>
__global__ __launch_bounds__(256) void gemm_mfma_kernel(const unsigned short* __restrict__ A,
                                                        const unsigned short* __restrict__ Wt,
                                                        const float* __restrict__ bias,
                                                        void* __restrict__ C,
                                                        int M, int Nc, int K) {
    __shared__ unsigned short As[4][64][8];   // [kc][row][j]
    __shared__ unsigned short Bs[4][64][8];   // [kc][col][j]
    int tid = threadIdx.x;
    int wave = tid >> 6, lane = tid & 63;
    int m0 = blockIdx.x * 64, n0 = blockIdx.y * 64;
    f32x4 acc[4];
#pragma unroll
    for (int c = 0; c < 4; ++c) acc[c] = (f32x4){0.f, 0.f, 0.f, 0.f};

    int sr = tid >> 2;        // staging row/col 0..63
    int sc = tid & 3;         // staging k-chunk 0..3
    int fr = lane & 15;       // fragment row/col
    int kc = lane >> 4;       // fragment k-chunk

    for (int k0 = 0; k0 < K; k0 += 32) {
        // stage A tile (64 rows x 32 k) -> As[kc][row][8]
        int gr = m0 + sr;
        ushort8v av = {0, 0, 0, 0, 0, 0, 0, 0};
        if (gr < M) av = *reinterpret_cast<const ushort8v*>(&A[(size_t)gr * K + k0 + sc * 8]);
        *reinterpret_cast<ushort8v*>(&As[sc][sr][0]) = av;
        // stage B tile (64 cols x 32 k) -> Bs[kc][col][8]
        ushort8v bv = *reinterpret_cast<const ushort8v*>(&Wt[(size_t)(n0 + sr) * K + k0 + sc * 8]);
        *reinterpret_cast<ushort8v*>(&Bs[sc][sr][0]) = bv;
        __syncthreads();

        bf16x8 af = __builtin_bit_cast(bf16x8,
            *reinterpret_cast<const ushort8v*>(&As[kc][wave * 16 + fr][0]));
#pragma unroll
        for (int c = 0; c < 4; ++c) {
            bf16x8 bf = __builtin_bit_cast(bf16x8,
                *reinterpret_cast<const ushort8v*>(&Bs[kc][c * 16 + fr][0]));
            acc[c] = __builtin_amdgcn_mfma_f32_16x16x32_bf16(af, bf, acc[c], 0, 0, 0);
        }
        __syncthreads();
    }

    // epilogue: D[row=(lane>>4)*4+j][col=lane&15] per 16x16 fragment
    int rg = lane >> 4;
#pragma unroll
    for (int c = 0; c < 4; ++c) {
        int col = n0 + c * 16 + fr;
        float b = bias[col];
#pragma unroll
        for (int j = 0; j < 4; ++j) {
            int row = m0 + wave * 16 + rg * 4 + j;
            if (row < M) {
                float v = fmaxf(acc[c][j] + b, 0.f);
                if (OUT_BF16)
                    ((unsigned short*)C)[(size_t)row * Nc + col] = f2bf(v);
                else
                    ((float*)C)[(size_t)row * Nc + col] = v;
            }
        }
    }
}

extern "C" void kernel_launch(void* const* d_in, const int* in_sizes, int n_in,
                              void* d_out, int out_size, void* d_ws, size_t ws_size,
                              hipStream_t stream) {
    const float* x = (const float*)d_in[0];
    const int* eb = (const int*)d_in[1];
    const int E = NEDGES;
    const int N = NNODES;

    const float* w1[3] = {(const float*)d_in[2], (const float*)d_in[6], (const float*)d_in[10]};
    const float* b1[3] = {(const float*)d_in[3], (const float*)d_in[7], (const float*)d_in[11]};
    const float* w2[3] = {(const float*)d_in[4], (const float*)d_in[8], (const float*)d_in[12]};
    const float* b2[3] = {(const float*)d_in[5], (const float*)d_in[9], (const float*)d_in[13]};

    // workspace layout
    char* ws = (char*)d_ws;
    size_t off = 0;
    auto alloc = [&](size_t bytes) {
        void* p = ws + off;
        off += (bytes + 255) & ~(size_t)255;
        return p;
    };
    int* flag   = (int*)alloc(4);
    int* cnt    = (int*)alloc((size_t)N * 4);
    int* offs   = (int*)alloc((size_t)(N + 1) * 4);
    int* cursor = (int*)alloc((size_t)N * 4);
    int* srcs   = (int*)alloc((size_t)E * 4);
    unsigned short* xb   = (unsigned short*)alloc((size_t)N * DIN * 2);
    unsigned short* zbuf = (unsigned short*)alloc((size_t)N * DH * 2);
    unsigned short* hbuf = (unsigned short*)alloc((size_t)N * DH * 2);
    unsigned short* tbuf = (unsigned short*)alloc((size_t)N * DH * 2);
    unsigned short* wt[6];
    wt[0] = (unsigned short*)alloc((size_t)DIN * DH * 2);          // w1_0^T: 256x128
    for (int i = 1; i < 6; ++i) wt[i] = (unsigned short*)alloc((size_t)DH * DH * 2);
    (void)ws_size; (void)n_in; (void)out_size; (void)in_sizes;

    // --- CSR build
    detect_i32_kernel<<<1, 256, 0, stream>>>(eb, 1024, flag);
    zero_i_kernel<<<(N + 255) / 256, 256, 0, stream>>>(cnt, N);
    hist_kernel<<<(E + 255) / 256, 256, 0, stream>>>(eb, flag, cnt, E);
    scan_kernel<<<1, 1024, 0, stream>>>(cnt, offs, cursor, N);
    scatter_kernel<<<(E + 255) / 256, 256, 0, stream>>>(eb, flag, cursor, srcs, E);

    // --- weight convert + transpose (all 6 at once)
    WconvArgs wa;
    wa.src[0] = w1[0]; wa.src[1] = w2[0]; wa.src[2] = w1[1];
    wa.src[3] = w2[1]; wa.src[4] = w1[2]; wa.src[5] = w2[2];
    for (int i = 0; i < 6; ++i) wa.dst[i] = wt[i];
    wa.kbits[0] = 7;
    for (int i = 1; i < 6; ++i) wa.kbits[i] = 8;
    wconv_kernel<<<dim3(256, 6), 256, 0, stream>>>(wa);

    // --- x -> bf16
    int x4 = N * DIN / 4;
    xconv_kernel<<<(x4 + 255) / 256, 256, 0, stream>>>(x, xb, x4);

    dim3 gemm_grid((N + 63) / 64, DH / 64);
    int agg_blocks_256 = ((N + 63) / 64) * 8;   // D=256: 64 nodes/block, 8 slices
    int agg_blocks_128 = ((N + 63) / 64) * 4;   // D=128: 64 nodes/block, 4 slices

    // --- layer 0 (D_in = 128)
    agg_add_sliced_kernel<128><<<agg_blocks_128, 256, 0, stream>>>(xb, srcs, offs, hbuf, N);
    gemm_mfma_kernel<1><<<gemm_grid, 256, 0, stream>>>(hbuf, wt[0], b1[0], tbuf, N, DH, DIN);
    gemm_mfma_kernel<1><<<gemm_grid, 256, 0, stream>>>(tbuf, wt[1], b2[0], zbuf, N, DH, DH);

    // --- layer 1
    agg_add_sliced_kernel<256><<<agg_blocks_256, 256, 0, stream>>>(zbuf, srcs, offs, hbuf, N);
    gemm_mfma_kernel<1><<<gemm_grid, 256, 0, stream>>>(hbuf, wt[2], b1[1], tbuf, N, DH, DH);
    gemm_mfma_kernel<1><<<gemm_grid, 256, 0, stream>>>(tbuf, wt[3], b2[1], zbuf, N, DH, DH);

    // --- layer 2 (final output fp32 to d_out)
    agg_add_sliced_kernel<256><<<agg_blocks_256, 256, 0, stream>>>(zbuf, srcs, offs, hbuf, N);
    gemm_mfma_kernel<1><<<gemm_grid, 256, 0, stream>>>(hbuf, wt[4], b1[2], tbuf, N, DH, DH);
    gemm_mfma_kernel<0><<<gemm_grid, 256, 0, stream>>>(tbuf, wt[5], b2[2], (float*)d_out, N, DH, DH);
}

// Round 5
// 186.098 us; speedup vs baseline: 1.8971x; 1.0015x over previous
//
#include <hip/hip_runtime.h>
#include <hip/hip_bf16.h>
#include <cstdint>

// ---------------------------------------------------------------------------
// GNN encoder: 3 x { agg = segment_sum(z[src], dst); h = z + agg;
//                    t = relu(h@w1+b1); z = relu(t@w2+b2) }
// CSR build per call (no float atomics). z kept in bf16 between layers.
// agg: feature-sliced gather (slice -> one XCD -> L2-resident) + 4-way unroll.
// MLP: BOTH GEMMs of a layer fused in one kernel; t lives in LDS only
// (wave w computes t rows w*16..w*16+15 = exactly its phase-2 A rows).
// Prep (zero/detect/xconv/wconv) fused into one kernel. 10 launches total.
// ---------------------------------------------------------------------------

#define NNODES 10000
#define NEDGES 320000
#define DIN 128
#define DH 256

typedef __bf16 bf16x8 __attribute__((ext_vector_type(8)));
typedef unsigned short ushort8v __attribute__((ext_vector_type(8)));
typedef unsigned short ushort4v __attribute__((ext_vector_type(4)));
typedef float f32x4 __attribute__((ext_vector_type(4)));

__device__ __forceinline__ unsigned short f2bf(float f) {
    unsigned int u = __float_as_uint(f);
    unsigned int r = u + 0x7fffu + ((u >> 16) & 1u);   // round-to-nearest-even
    return (unsigned short)(r >> 16);
}
__device__ __forceinline__ float bf2f(unsigned short u) {
    return __uint_as_float(((unsigned int)u) << 16);
}

// --- fused prep: [0,40) zero cnt | [40] detect i32/i64 | [41,1291) xconv |
// [1291,2699) wconv (6 matrices, fp32 [K][256] -> bf16 [256][K])
struct PrepArgs {
    const float* wsrc[6];
    unsigned short* wdst[6];
    int wkbits[6];
    const int* eb;
    int* flag;
    int* cnt;
    const float* x;
    unsigned short* xb;
};
#define PREP_ZERO_B 40
#define PREP_XCONV_B 1250
#define PREP_WCONV_B 1408
#define PREP_GRID (PREP_ZERO_B + 1 + PREP_XCONV_B + PREP_WCONV_B)

__global__ void prep_kernel(PrepArgs a) {
    int bid = blockIdx.x;
    int tid = threadIdx.x;
    if (bid < PREP_ZERO_B) {
        int i = bid * 256 + tid;
        if (i < NNODES) a.cnt[i] = 0;
    } else if (bid == PREP_ZERO_B) {
        __shared__ int any;
        if (tid == 0) any = 0;
        __syncthreads();
        for (int i = tid; i < 1024; i += 256)
            if (a.eb[2 * i + 1] != 0) any = 1;
        __syncthreads();
        if (tid == 0) a.flag[0] = any;   // 1 => int32 storage, 0 => int64
    } else if (bid < PREP_ZERO_B + 1 + PREP_XCONV_B) {
        int i = (bid - PREP_ZERO_B - 1) * 256 + tid;
        if (i < NNODES * DIN / 4) {
            float4 v = reinterpret_cast<const float4*>(a.x)[i];
            ushort4v o = {f2bf(v.x), f2bf(v.y), f2bf(v.z), f2bf(v.w)};
            reinterpret_cast<ushort4v*>(a.xb)[i] = o;
        }
    } else {
        int wb = bid - (PREP_ZERO_B + 1 + PREP_XCONV_B);
        int m, wblock;
        if (wb < 128) { m = 0; wblock = wb; }
        else { m = 1 + (wb - 128) / 256; wblock = (wb - 128) & 255; }
        int kb = a.wkbits[m];
        int K = 1 << kb;
        int idx = wblock * 256 + tid;
        int nn = idx >> kb;         // output row (col of src)
        int kk = idx & (K - 1);     // output col (row of src)
        a.wdst[m][idx] = f2bf(a.wsrc[m][(size_t)kk * 256 + nn]);
    }
}

__device__ __forceinline__ int eload(const int* __restrict__ eb, int is32, long logical_idx) {
    return is32 ? eb[logical_idx] : eb[2 * logical_idx]; // little-endian low word
}

__global__ void hist_kernel(const int* __restrict__ eb, const int* __restrict__ flag,
                            int* __restrict__ cnt, int E) {
    int i = blockIdx.x * blockDim.x + threadIdx.x;
    if (i >= E) return;
    int is32 = flag[0];
    int d = eload(eb, is32, (long)E + i);
    atomicAdd(&cnt[d], 1);
}

// single-block exclusive scan over N counts -> offs[N+1], cursor copy
__global__ __launch_bounds__(1024) void scan_kernel(const int* __restrict__ cnt,
                                                    int* __restrict__ offs,
                                                    int* __restrict__ cursor, int n) {
    __shared__ int sums[1024];
    int tid = threadIdx.x;
    int per = (n + 1023) / 1024;          // 10 for n=10000
    int beg = tid * per;
    int local[16];
    int s = 0;
    for (int i = 0; i < per; ++i) {
        int idx = beg + i;
        int v = (idx < n) ? cnt[idx] : 0;
        local[i] = s;
        s += v;
    }
    sums[tid] = s;
    __syncthreads();
    for (int d = 1; d < 1024; d <<= 1) {
        int y = (tid >= d) ? sums[tid - d] : 0;
        __syncthreads();
        sums[tid] += y;
        __syncthreads();
    }
    int base = sums[tid] - s;             // exclusive prefix of this thread's chunk
    for (int i = 0; i < per; ++i) {
        int idx = beg + i;
        if (idx < n) {
            int v = base + local[i];
            offs[idx] = v;
            cursor[idx] = v;
        }
    }
    if (tid == 1023) offs[n] = sums[1023];
}

__global__ void scatter_kernel(const int* __restrict__ eb, const int* __restrict__ flag,
                               int* __restrict__ cursor, int* __restrict__ srcs, int E) {
    int i = blockIdx.x * blockDim.x + threadIdx.x;
    if (i >= E) return;
    int is32 = flag[0];
    int s = eload(eb, is32, (long)i);
    int d = eload(eb, is32, (long)E + i);
    int pos = atomicAdd(&cursor[d], 1);
    srcs[pos] = s;
}

// --- sliced bf16 aggregation: h[i] = z[i] + sum_{e in CSR[i]} z[src_e].
// NSLICE feature slices; slice = bid & (NSLICE-1) -> round-robin XCD binding;
// per-XCD working set N*64B = 0.64 MB (L2-hot). 4 independent gather chains.
template <int D>
__global__ __launch_bounds__(256) void agg_add_sliced_kernel(const unsigned short* __restrict__ z,
                                                             const int* __restrict__ srcs,
                                                             const int* __restrict__ offs,
                                                             unsigned short* __restrict__ h, int n) {
    constexpr int NSLICE = (D == 256) ? 8 : 4;
    constexpr int SLICE_E = D / NSLICE;   // 32 elems per slice
    constexpr int LPN = SLICE_E / 8;      // 4 lanes per node (ushort8 each)
    constexpr int NPB = 256 / LPN;        // 64 nodes per block
    int bid = blockIdx.x;
    int slice = bid & (NSLICE - 1);
    int ng = bid / NSLICE;
    int t = threadIdx.x;
    int node = ng * NPB + t / LPN;
    if (node >= n) return;
    int li = t % LPN;
    int col8 = slice * LPN + li;          // ushort8 column index within row
    const ushort8v* zb = reinterpret_cast<const ushort8v*>(z);
    const int ld8 = D / 8;
    int beg = offs[node], end = offs[node + 1];

    float a0[8] = {}, a1[8] = {}, a2[8] = {}, a3[8] = {};
    int e = beg;
    for (; e + 4 <= end; e += 4) {
        int s0 = srcs[e], s1 = srcs[e + 1], s2 = srcs[e + 2], s3 = srcs[e + 3];
        ushort8v v0 = zb[(size_t)s0 * ld8 + col8];
        ushort8v v1 = zb[(size_t)s1 * ld8 + col8];
        ushort8v v2 = zb[(size_t)s2 * ld8 + col8];
        ushort8v v3 = zb[(size_t)s3 * ld8 + col8];
#pragma unroll
        for (int j = 0; j < 8; ++j) {
            a0[j] += bf2f(v0[j]);
            a1[j] += bf2f(v1[j]);
            a2[j] += bf2f(v2[j]);
            a3[j] += bf2f(v3[j]);
        }
    }
    for (; e < end; ++e) {
        ushort8v v = zb[(size_t)srcs[e] * ld8 + col8];
#pragma unroll
        for (int j = 0; j < 8; ++j) a0[j] += bf2f(v[j]);
    }
    ushort8v zr = zb[(size_t)node * ld8 + col8];   // residual z term
    ushort8v o;
#pragma unroll
    for (int j = 0; j < 8; ++j) {
        float v = a0[j] + a1[j] + a2[j] + a3[j] + bf2f(zr[j]);
        o[j] = f2bf(v);
    }
    reinterpret_cast<ushort8v*>(h)[(size_t)node * ld8 + col8] = o;
}

// --- fused MLP: C = relu( relu(A@W1+b1) @ W2 + b2 ).
// A: MxK bf16, Wt1: 256xK bf16 (transposed), Wt2: 256x256 bf16 (transposed).
// Block = 64 rows x 256 cols, 4 waves; wave w owns rows w*16..w*16+15 in BOTH
// phases, so t stays in LDS (fragment-ordered Ts). Per wave: 16 f32x4 accs.
// MFMA layouts (m89-verified): A-frag row=lane&15, k=(lane>>4)*8+j;
// C/D col=lane&15, row=(lane>>4)*4+j.
template <int K, int OUT_BF16>
__global__ __launch_bounds__(256) void mlp_fused_kernel(const unsigned short* __restrict__ A,
                                                        const unsigned short* __restrict__ Wt1,
                                                        const float* __restrict__ b1,
                                                        const unsigned short* __restrict__ Wt2,
                                                        const float* __restrict__ b2,
                                                        void* __restrict__ C, int M) {
    __shared__ unsigned short As[4][64][8];      // 4 KB   [kc][row][j]
    __shared__ unsigned short Bs[4][256][8];     // 16 KB  [kc][col][j]
    __shared__ unsigned short Ts[8][4][64][8];   // 32 KB  Ts[a][b][r][c] = t[r][a*32+b*8+c]
    int tid = threadIdx.x;
    int wave = tid >> 6, lane = tid & 63;
    int m0 = blockIdx.x * 64;
    int fr = lane & 15;        // fragment row/col
    int kc = lane >> 4;        // fragment k-chunk (== rg for C/D rows)
    int sr = tid >> 2;         // staging row 0..63
    int scn = tid & 3;         // staging k-chunk 0..3

    f32x4 acc[16];
#pragma unroll
    for (int c = 0; c < 16; ++c) acc[c] = (f32x4){0.f, 0.f, 0.f, 0.f};

    // ---- phase 1: t = relu(A @ W1 + b1), t in Ts
    for (int k0 = 0; k0 < K; k0 += 32) {
        int gr = m0 + sr;
        ushort8v av = {0, 0, 0, 0, 0, 0, 0, 0};
        if (gr < M) av = *reinterpret_cast<const ushort8v*>(&A[(size_t)gr * K + k0 + scn * 8]);
        *reinterpret_cast<ushort8v*>(&As[scn][sr][0]) = av;
#pragma unroll
        for (int cp = 0; cp < 4; ++cp) {
            int col = cp * 64 + sr;
            ushort8v bv = *reinterpret_cast<const ushort8v*>(&Wt1[(size_t)col * K + k0 + scn * 8]);
            *reinterpret_cast<ushort8v*>(&Bs[scn][col][0]) = bv;
        }
        __syncthreads();
        bf16x8 af = __builtin_bit_cast(bf16x8,
            *reinterpret_cast<const ushort8v*>(&As[kc][wave * 16 + fr][0]));
#pragma unroll
        for (int cf = 0; cf < 16; ++cf) {
            bf16x8 bf = __builtin_bit_cast(bf16x8,
                *reinterpret_cast<const ushort8v*>(&Bs[kc][cf * 16 + fr][0]));
            acc[cf] = __builtin_amdgcn_mfma_f32_16x16x32_bf16(af, bf, acc[cf], 0, 0, 0);
        }
        __syncthreads();
    }
    // epilogue 1 -> Ts (scalar b16 writes; one-time cost per block)
#pragma unroll
    for (int cf = 0; cf < 16; ++cf) {
        int col = cf * 16 + fr;
        float bb = b1[col];
#pragma unroll
        for (int j = 0; j < 4; ++j) {
            int row = wave * 16 + kc * 4 + j;
            float v = fmaxf(acc[cf][j] + bb, 0.f);
            Ts[cf >> 1][((cf & 1) << 1) | (fr >> 3)][row][fr & 7] = f2bf(v);
        }
        acc[cf] = (f32x4){0.f, 0.f, 0.f, 0.f};
    }
    __syncthreads();

    // ---- phase 2: z = relu(t @ W2 + b2); A-frags read from own wave's Ts rows
    for (int k20 = 0; k20 < 8; ++k20) {
#pragma unroll
        for (int cp = 0; cp < 4; ++cp) {
            int col = cp * 64 + sr;
            ushort8v bv = *reinterpret_cast<const ushort8v*>(&Wt2[(size_t)col * 256 + k20 * 32 + scn * 8]);
            *reinterpret_cast<ushort8v*>(&Bs[scn][col][0]) = bv;
        }
        __syncthreads();
        bf16x8 af = __builtin_bit_cast(bf16x8,
            *reinterpret_cast<const ushort8v*>(&Ts[k20][kc][wave * 16 + fr][0]));
#pragma unroll
        for (int cf = 0; cf < 16; ++cf) {
            bf16x8 bf = __builtin_bit_cast(bf16x8,
                *reinterpret_cast<const ushort8v*>(&Bs[kc][cf * 16 + fr][0]));
            acc[cf] = __builtin_amdgcn_mfma_f32_16x16x32_bf16(af, bf, acc[cf], 0, 0, 0);
        }
        __syncthreads();
    }
    // epilogue 2 -> global
#pragma unroll
    for (int cf = 0; cf < 16; ++cf) {
        int col = cf * 16 + fr;
        float bb = b2[col];
#pragma unroll
        for (int j = 0; j < 4; ++j) {
            int row = m0 + wave * 16 + kc * 4 + j;
            if (row < M) {
                float v = fmaxf(acc[cf][j] + bb, 0.f);
                if (OUT_BF16)
                    ((unsigned short*)C)[(size_t)row * 256 + col] = f2bf(v);
                else
                    ((float*)C)[(size_t)row * 256 + col] = v;
            }
        }
    }
}

extern "C" void kernel_launch(void* const* d_in, const int* in_sizes, int n_in,
                              void* d_out, int out_size, void* d_ws, size_t ws_size,
                              hipStream_t stream) {
    const float* x = (const float*)d_in[0];
    const int* eb = (const int*)d_in[1];
    const int E = NEDGES;
    const int N = NNODES;

    const float* w1[3] = {(const float*)d_in[2], (const float*)d_in[6], (const float*)d_in[10]};
    const float* b1[3] = {(const float*)d_in[3], (const float*)d_in[7], (const float*)d_in[11]};
    const float* w2[3] = {(const float*)d_in[4], (const float*)d_in[8], (const float*)d_in[12]};
    const float* b2[3] = {(const float*)d_in[5], (const float*)d_in[9], (const float*)d_in[13]};

    // workspace layout
    char* ws = (char*)d_ws;
    size_t off = 0;
    auto alloc = [&](size_t bytes) {
        void* p = ws + off;
        off += (bytes + 255) & ~(size_t)255;
        return p;
    };
    int* flag   = (int*)alloc(4);
    int* cnt    = (int*)alloc((size_t)N * 4);
    int* offs   = (int*)alloc((size_t)(N + 1) * 4);
    int* cursor = (int*)alloc((size_t)N * 4);
    int* srcs   = (int*)alloc((size_t)E * 4);
    unsigned short* xb   = (unsigned short*)alloc((size_t)N * DIN * 2);
    unsigned short* zbuf = (unsigned short*)alloc((size_t)N * DH * 2);
    unsigned short* hbuf = (unsigned short*)alloc((size_t)N * DH * 2);
    unsigned short* wt[6];
    wt[0] = (unsigned short*)alloc((size_t)DIN * DH * 2);          // w1_0^T: 256x128
    for (int i = 1; i < 6; ++i) wt[i] = (unsigned short*)alloc((size_t)DH * DH * 2);
    (void)ws_size; (void)n_in; (void)out_size; (void)in_sizes;

    // --- fused prep (zero cnt | detect | x->bf16 | weights ->bf16 transposed)
    PrepArgs pa;
    pa.wsrc[0] = w1[0]; pa.wsrc[1] = w2[0]; pa.wsrc[2] = w1[1];
    pa.wsrc[3] = w2[1]; pa.wsrc[4] = w1[2]; pa.wsrc[5] = w2[2];
    for (int i = 0; i < 6; ++i) pa.wdst[i] = wt[i];
    pa.wkbits[0] = 7;
    for (int i = 1; i < 6; ++i) pa.wkbits[i] = 8;
    pa.eb = eb; pa.flag = flag; pa.cnt = cnt; pa.x = x; pa.xb = xb;
    prep_kernel<<<PREP_GRID, 256, 0, stream>>>(pa);

    // --- CSR build
    hist_kernel<<<(E + 255) / 256, 256, 0, stream>>>(eb, flag, cnt, E);
    scan_kernel<<<1, 1024, 0, stream>>>(cnt, offs, cursor, N);
    scatter_kernel<<<(E + 255) / 256, 256, 0, stream>>>(eb, flag, cursor, srcs, E);

    int mlp_grid = (N + 63) / 64;               // 157 blocks
    int agg_blocks_256 = ((N + 63) / 64) * 8;   // D=256: 64 nodes/block, 8 slices
    int agg_blocks_128 = ((N + 63) / 64) * 4;   // D=128: 64 nodes/block, 4 slices

    // --- layer 0 (K = 128)
    agg_add_sliced_kernel<128><<<agg_blocks_128, 256, 0, stream>>>(xb, srcs, offs, hbuf, N);
    mlp_fused_kernel<128, 1><<<mlp_grid, 256, 0, stream>>>(hbuf, wt[0], b1[0], wt[1], b2[0], zbuf, N);

    // --- layer 1
    agg_add_sliced_kernel<256><<<agg_blocks_256, 256, 0, stream>>>(zbuf, srcs, offs, hbuf, N);
    mlp_fused_kernel<256, 1><<<mlp_grid, 256, 0, stream>>>(hbuf, wt[2], b1[1], wt[3], b2[1], zbuf, N);

    // --- layer 2 (final output fp32 to d_out)
    agg_add_sliced_kernel<256><<<agg_blocks_256, 256, 0, stream>>>(zbuf, srcs, offs, hbuf, N);
    mlp_fused_kernel<256, 0><<<mlp_grid, 256, 0, stream>>>(hbuf, wt[4], b1[2], wt[5], b2[2], (float*)d_out, N);
}